// Round 3
// baseline (2459.610 us; speedup 1.0000x reference)
//
#include <hip/hip_runtime.h>
#include <hip/hip_bf16.h>

// Sizes
#define U_    1200
#define E_    620
#define B_    128
#define T_    64
#define N3    3600           // 3*U
#define NP    3712           // padded 3U = 29*128
#define KE    640            // padded E  = 10*64
#define KU    1216           // padded U  = 19*64
#define LN_EPS 1e-3f

typedef __attribute__((ext_vector_type(8))) short short8;
typedef __attribute__((ext_vector_type(4))) float f32x4;

// ---------------- workspace layout (bytes) ----------------
constexpr size_t OFF_EMBH  = 0;                                   // bf16 [8192][KE] hi
constexpr size_t SZ_EMB    = (size_t)8192 * KE * 2;
constexpr size_t OFF_EMBL  = OFF_EMBH + SZ_EMB;                   // bf16 [8192][KE] lo
constexpr size_t OFF_KTH   = OFF_EMBL + SZ_EMB;                   // bf16 [2][NP][KE] hi
constexpr size_t SZ_KT     = (size_t)2 * NP * KE * 2;
constexpr size_t OFF_KTL   = OFF_KTH + SZ_KT;                     // lo
constexpr size_t OFF_RKTH  = OFF_KTL + SZ_KT;                     // bf16 [2][NP][KU] hi
constexpr size_t SZ_RKT    = (size_t)2 * NP * KU * 2;
constexpr size_t OFF_RKTL  = OFF_RKTH + SZ_RKT;                   // lo
constexpr size_t OFF_INNER = OFF_RKTL + SZ_RKT;                   // f32 [2][2][128][NP]
constexpr size_t SZ_INNER  = (size_t)2 * 2 * B_ * NP * 4;
constexpr size_t OFF_HLN   = OFF_INNER + SZ_INNER;                // f32 [2][128][U]
constexpr size_t SZ_HLN    = (size_t)2 * B_ * U_ * 4;
constexpr size_t OFF_HLNBH = OFF_HLN + SZ_HLN;                    // bf16 [2][128][KU] hi
constexpr size_t SZ_HLNB   = (size_t)2 * B_ * KU * 2;
constexpr size_t OFF_HLNBL = OFF_HLNBH + SZ_HLNB;                 // lo

__device__ inline void lds_load16(const void* g, void* l) {
  __builtin_amdgcn_global_load_lds(
      (const __attribute__((address_space(1))) unsigned int*)g,
      (__attribute__((address_space(3))) unsigned int*)l, 16, 0, 0);
}

__device__ inline float sigmf(float x) { return 1.f / (1.f + expf(-x)); }

// ---------------- K1: embedding gather + tanh (fp32 out + hi/lo bf16) -----
__global__ __launch_bounds__(256)
void embed_kernel(const int* __restrict__ sent, const float* __restrict__ embed,
                  float* __restrict__ out_emb,
                  __hip_bfloat16* __restrict__ embH, __hip_bfloat16* __restrict__ embL) {
  const int row = blockIdx.x;                 // b*T + t
  const int idx = sent[row];
  const float* src = embed + (size_t)idx * E_;
  for (int e = threadIdx.x; e < KE; e += 256) {
    float v = 0.f;
    if (e < E_) {
      v = tanhf(src[e]);
      out_emb[(size_t)row * E_ + e] = v;
    }
    const __hip_bfloat16 hi = __float2bfloat16(v);
    embH[(size_t)row * KE + e] = hi;
    embL[(size_t)row * KE + e] = __float2bfloat16(v - __bfloat162float(hi));
  }
}

// ---------------- K2: transpose+cast [K][3600]f32 -> [NP][Kp] hi/lo bf16 ---
__global__ __launch_bounds__(256)
void transpose_cast(const float* __restrict__ W0, const float* __restrict__ W1,
                    __hip_bfloat16* __restrict__ WtHi, __hip_bfloat16* __restrict__ WtLo,
                    int Kreal, int Kp) {
  const int d = blockIdx.z;
  const float* W = d ? W1 : W0;
  __hip_bfloat16* dstH = WtHi + (size_t)d * NP * Kp;
  __hip_bfloat16* dstL = WtLo + (size_t)d * NP * Kp;
  __shared__ float tile[32][33];
  const int n0 = blockIdx.x * 32, k0 = blockIdx.y * 32;
  const int tx = threadIdx.x, ty = threadIdx.y;   // 32 x 8
#pragma unroll
  for (int i = 0; i < 32; i += 8) {
    const int k = k0 + ty + i, n = n0 + tx;
    tile[ty + i][tx] = (k < Kreal && n < N3) ? W[(size_t)k * N3 + n] : 0.f;
  }
  __syncthreads();
#pragma unroll
  for (int i = 0; i < 32; i += 8) {
    const int n = n0 + ty + i, k = k0 + tx;
    const float v = tile[tx][ty + i];
    const __hip_bfloat16 hi = __float2bfloat16(v);
    dstH[(size_t)n * Kp + k] = hi;
    dstL[(size_t)n * Kp + k] = __float2bfloat16(v - __bfloat162float(hi));
  }
}

// ---------------- K4: init h_ln = LN(0) = beta ----------------
__global__ __launch_bounds__(256)
void init_hln(const float* __restrict__ fw_b0, const float* __restrict__ bw_b0,
              float* __restrict__ hln, __hip_bfloat16* __restrict__ hlnbH,
              __hip_bfloat16* __restrict__ hlnbL) {
  const int idx = blockIdx.x * 256 + threadIdx.x;   // [2*128*KU]
  if (idx >= 2 * B_ * KU) return;
  const int k = idx % KU;
  const int rowd = idx / KU;
  const int d = rowd >> 7;
  float v = 0.f;
  if (k < U_) {
    v = (d ? bw_b0 : fw_b0)[k];
    hln[(size_t)rowd * U_ + k] = v;
  }
  const __hip_bfloat16 hi = __float2bfloat16(v);
  hlnbH[idx] = hi;
  hlnbL[idx] = __float2bfloat16(v - __bfloat162float(hi));
}

// ---------------- step GEMM: two fp32 planes per dir ----------------------
// grid (NP/64, B/64, 4): z = d*2 + which. which=0: rec = h_ln @ rkernel^T
// (K=KU); which=1: x = emb_t @ kernel^T (K=KE). Full split precision:
// 4 MFMA products (hh, hl, lh, ll) -> ~fp32 accuracy. C: inner[(d*2+w)][B][NP].
__global__ __launch_bounds__(256)
void step_gemm(const __hip_bfloat16* __restrict__ embH, const __hip_bfloat16* __restrict__ embL,
               const __hip_bfloat16* __restrict__ hlnbH, const __hip_bfloat16* __restrict__ hlnbL,
               const __hip_bfloat16* __restrict__ rkTH, const __hip_bfloat16* __restrict__ rkTL,
               const __hip_bfloat16* __restrict__ kTH, const __hip_bfloat16* __restrict__ kTL,
               float* __restrict__ inner, int t) {
  constexpr int BM = 64, BN = 64, BK = 64;
  constexpr int WM = BM / 2, WN = BN / 2, FM = WM / 16, FN = WN / 16;  // 2,2
  constexpr int TA = BM * BK, TB = BN * BK;                            // 4096
  const int z = blockIdx.z;
  const int d = z >> 1, w = z & 1;
  const int tx = d ? (T_ - 1 - t) : t;
  const int ldk = w ? KE : KU;
  const int ksteps = w ? (KE / BK) : (KU / BK);

  const __hip_bfloat16* AH = w ? embH : hlnbH;
  const __hip_bfloat16* AL = w ? embL : hlnbL;
  const __hip_bfloat16* BH = (w ? kTH : rkTH) + (size_t)d * NP * ldk;
  const __hip_bfloat16* BL = (w ? kTL : rkTL) + (size_t)d * NP * ldk;

  const int m0 = blockIdx.y * BM;
  const int n0 = blockIdx.x * BN;
  const int tid = threadIdx.x;
  const int lane = tid & 63;
  const int wid = tid >> 6;
  const int wr = wid >> 1, wc = wid & 1;

  __shared__ __align__(16) __hip_bfloat16 As[2 * TA];
  __shared__ __align__(16) __hip_bfloat16 Bs[2 * TB];

  f32x4 acc[FM][FN] = {};

  const int srow = tid >> 3;           // 0..31: row within 32-row slab
  const int scol = (tid & 7) << 3;     // 8-elem col group

  for (int ks = 0; ks < ksteps; ++ks) {
    const int k0 = ks * BK;
    __syncthreads();
#pragma unroll
    for (int it = 0; it < TA / 2048; ++it) {
      const int row = m0 + it * 32 + srow;     // batch index
      const size_t goff = w ? ((size_t)(row * T_ + tx) * KE + k0 + scol)
                            : ((size_t)(d * B_ + row) * KU + k0 + scol);
      lds_load16(AH + goff, As + it * 2048 + tid * 8);
      lds_load16(AL + goff, As + TA + it * 2048 + tid * 8);
    }
#pragma unroll
    for (int it = 0; it < TB / 2048; ++it) {
      const size_t goff = (size_t)(n0 + it * 32 + srow) * ldk + k0 + scol;
      lds_load16(BH + goff, Bs + it * 2048 + tid * 8);
      lds_load16(BL + goff, Bs + TB + it * 2048 + tid * 8);
    }
    __syncthreads();
#pragma unroll
    for (int kk = 0; kk < BK / 32; ++kk) {
      short8 ah[FM], al[FM], bh[FN], bl[FN];
#pragma unroll
      for (int mi = 0; mi < FM; ++mi) {
        const int off = (wr * WM + mi * 16 + (lane & 15)) * BK + kk * 32 + (lane >> 4) * 8;
        ah[mi] = *(const short8*)(As + off);
        al[mi] = *(const short8*)(As + TA + off);
      }
#pragma unroll
      for (int ni = 0; ni < FN; ++ni) {
        const int off = (wc * WN + ni * 16 + (lane & 15)) * BK + kk * 32 + (lane >> 4) * 8;
        bh[ni] = *(const short8*)(Bs + off);
        bl[ni] = *(const short8*)(Bs + TB + off);
      }
#pragma unroll
      for (int mi = 0; mi < FM; ++mi)
#pragma unroll
        for (int ni = 0; ni < FN; ++ni) {
          acc[mi][ni] = __builtin_amdgcn_mfma_f32_16x16x32_bf16(ah[mi], bh[ni], acc[mi][ni], 0, 0, 0);
          acc[mi][ni] = __builtin_amdgcn_mfma_f32_16x16x32_bf16(ah[mi], bl[ni], acc[mi][ni], 0, 0, 0);
          acc[mi][ni] = __builtin_amdgcn_mfma_f32_16x16x32_bf16(al[mi], bh[ni], acc[mi][ni], 0, 0, 0);
          acc[mi][ni] = __builtin_amdgcn_mfma_f32_16x16x32_bf16(al[mi], bl[ni], acc[mi][ni], 0, 0, 0);
        }
    }
  }

  // epilogue: C/D layout col=lane&15, row=(lane>>4)*4+j
  float* C = inner + (size_t)z * B_ * NP;
#pragma unroll
  for (int mi = 0; mi < FM; ++mi)
#pragma unroll
    for (int ni = 0; ni < FN; ++ni) {
      const int gc = n0 + wc * WN + ni * 16 + (lane & 15);
      const int gr = m0 + wr * WM + mi * 16 + ((lane >> 4) << 2);
#pragma unroll
      for (int j = 0; j < 4; ++j)
        C[(size_t)(gr + j) * NP + gc] = acc[mi][ni][j];
    }
}

// ---------------- block-wide 2-value sum reduction ----------------
__device__ inline void breduce2(float& a, float& b, float* red, int tid) {
#pragma unroll
  for (int off = 32; off; off >>= 1) {
    a += __shfl_down(a, off, 64);
    b += __shfl_down(b, off, 64);
  }
  const int w = tid >> 6;
  __syncthreads();
  if ((tid & 63) == 0) { red[w] = a; red[4 + w] = b; }
  __syncthreads();
  a = red[0] + red[1] + red[2] + red[3];
  b = red[4] + red[5] + red[6] + red[7];
}

// ---------------- K6: per-row GRU update (one block per (dir,row)) --------
__global__ __launch_bounds__(256)
void gru_update(const float* __restrict__ inner,
                const float* __restrict__ fw_bias, const float* __restrict__ bw_bias,
                const float* __restrict__ fw_ln0g, const float* __restrict__ fw_ln0b,
                const float* __restrict__ fw_ln3g, const float* __restrict__ fw_ln3b,
                const float* __restrict__ bw_ln0g, const float* __restrict__ bw_ln0b,
                const float* __restrict__ bw_ln3g, const float* __restrict__ bw_ln3b,
                float* __restrict__ hln, __hip_bfloat16* __restrict__ hlnbH,
                __hip_bfloat16* __restrict__ hlnbL,
                float* __restrict__ out_tv, int t) {
  const int bid = blockIdx.x;
  const int d = bid >> 7;
  const int r = bid & 127;
  const int tid = threadIdx.x;

  const float* rec_r = inner + ((size_t)(d * 2 + 0) * B_ + r) * NP;
  const float* x_r   = inner + ((size_t)(d * 2 + 1) * B_ + r) * NP;
  const float* ib = d ? bw_bias : fw_bias;          // input bias (row 0)
  const float* rb = ib + N3;                        // recurrent bias (row 1)
  const float* g0 = d ? bw_ln0g : fw_ln0g;
  const float* b0 = d ? bw_ln0b : fw_ln0b;
  const float* g3 = d ? bw_ln3g : fw_ln3g;
  const float* b3 = d ? bw_ln3b : fw_ln3b;
  float* hl = hln + ((size_t)d * B_ + r) * U_;
  __hip_bfloat16* hlbH = hlnbH + ((size_t)d * B_ + r) * KU;
  __hip_bfloat16* hlbL = hlnbL + ((size_t)d * B_ + r) * KU;

  __shared__ float red[8];

  float zv[5], cv[5], hv[5];
  float s1 = 0.f, s2 = 0.f;
#pragma unroll
  for (int i = 0; i < 5; ++i) {
    const int c = tid + i * 256;
    if (c < U_) {
      const float z  = sigmf(x_r[c] + ib[c] + rec_r[c] + rb[c]);
      const float rr = sigmf(x_r[U_ + c] + ib[U_ + c] + rec_r[U_ + c] + rb[U_ + c]);
      const float cand = (x_r[2 * U_ + c] + ib[2 * U_ + c]) +
                         rr * (rec_r[2 * U_ + c] + rb[2 * U_ + c]);
      zv[i] = z; cv[i] = cand;
      s1 += cand; s2 += cand * cand;
    }
  }
  breduce2(s1, s2, red, tid);
  const float m1 = s1 / U_;
  const float is1 = rsqrtf(s2 / U_ - m1 * m1 + LN_EPS);

  float t1 = 0.f, t2 = 0.f;
#pragma unroll
  for (int i = 0; i < 5; ++i) {
    const int c = tid + i * 256;
    if (c < U_) {
      const float hh = tanhf(g3[c] * (cv[i] - m1) * is1 + b3[c]);
      const float hn = zv[i] * hl[c] + (1.f - zv[i]) * hh;
      hv[i] = hn;
      t1 += hn; t2 += hn * hn;
    }
  }
  breduce2(t1, t2, red, tid);
  const float m2 = t1 / U_;
  const float is2 = rsqrtf(t2 / U_ - m2 * m2 + LN_EPS);

#pragma unroll
  for (int i = 0; i < 5; ++i) {
    const int c = tid + i * 256;
    if (c < U_) {
      const float hlnew = g0[c] * (hv[i] - m2) * is2 + b0[c];
      hl[c] = hlnew;
      const __hip_bfloat16 hi = __float2bfloat16(hlnew);
      hlbH[c] = hi;
      hlbL[c] = __float2bfloat16(hlnew - __bfloat162float(hi));
      if (t == T_ - 1) out_tv[(size_t)r * 2400 + (size_t)d * U_ + c] = hv[i];
    }
  }
}

// ---------------- host-side launch ----------------
extern "C" void kernel_launch(void* const* d_in, const int* in_sizes, int n_in,
                              void* d_out, int out_size, void* d_ws, size_t ws_size,
                              hipStream_t stream) {
  const int*   sent      = (const int*)  d_in[0];
  const float* embed     = (const float*)d_in[1];
  const float* fw_kernel = (const float*)d_in[2];
  const float* fw_rkern  = (const float*)d_in[3];
  const float* fw_bias   = (const float*)d_in[4];
  const float* fw_ln0g   = (const float*)d_in[5];
  const float* fw_ln0b   = (const float*)d_in[6];
  const float* fw_ln3g   = (const float*)d_in[7];
  const float* fw_ln3b   = (const float*)d_in[8];
  const float* bw_kernel = (const float*)d_in[9];
  const float* bw_rkern  = (const float*)d_in[10];
  const float* bw_bias   = (const float*)d_in[11];
  const float* bw_ln0g   = (const float*)d_in[12];
  const float* bw_ln0b   = (const float*)d_in[13];
  const float* bw_ln3g   = (const float*)d_in[14];
  const float* bw_ln3b   = (const float*)d_in[15];

  uint8_t* ws = (uint8_t*)d_ws;
  __hip_bfloat16* embH  = (__hip_bfloat16*)(ws + OFF_EMBH);
  __hip_bfloat16* embL  = (__hip_bfloat16*)(ws + OFF_EMBL);
  __hip_bfloat16* kTH   = (__hip_bfloat16*)(ws + OFF_KTH);
  __hip_bfloat16* kTL   = (__hip_bfloat16*)(ws + OFF_KTL);
  __hip_bfloat16* rkTH  = (__hip_bfloat16*)(ws + OFF_RKTH);
  __hip_bfloat16* rkTL  = (__hip_bfloat16*)(ws + OFF_RKTL);
  float*          inner = (float*)(ws + OFF_INNER);
  float*          hln   = (float*)(ws + OFF_HLN);
  __hip_bfloat16* hlnbH = (__hip_bfloat16*)(ws + OFF_HLNBH);
  __hip_bfloat16* hlnbL = (__hip_bfloat16*)(ws + OFF_HLNBL);

  float* out_tv  = (float*)d_out;                        // [128][2400]
  float* out_emb = (float*)d_out + (size_t)B_ * 2 * U_;  // [8192][620]

  // K1: embedding gather + tanh (fp32 + hi/lo bf16 planes)
  embed_kernel<<<B_ * T_, 256, 0, stream>>>(sent, embed, out_emb, embH, embL);

  // K2: weight transpose+cast hi/lo (both dirs each)
  transpose_cast<<<dim3(NP / 32, KE / 32, 2), dim3(32, 8), 0, stream>>>(
      fw_kernel, bw_kernel, kTH, kTL, E_, KE);
  transpose_cast<<<dim3(NP / 32, KU / 32, 2), dim3(32, 8), 0, stream>>>(
      fw_rkern, bw_rkern, rkTH, rkTL, U_, KU);

  // K4: h_ln = LN(0) = beta
  init_hln<<<(2 * B_ * KU + 255) / 256, 256, 0, stream>>>(fw_ln0b, bw_ln0b,
                                                          hln, hlnbH, hlnbL);

  // scan: per-step split GEMMs (rec K=1216, x K=640) + fused pointwise update
  for (int t = 0; t < T_; ++t) {
    step_gemm<<<dim3(NP / 64, B_ / 64, 4), 256, 0, stream>>>(
        embH, embL, hlnbH, hlnbL, rkTH, rkTL, kTH, kTL, inner, t);
    gru_update<<<2 * B_, 256, 0, stream>>>(
        inner, fw_bias, bw_bias,
        fw_ln0g, fw_ln0b, fw_ln3g, fw_ln3b,
        bw_ln0g, bw_ln0b, bw_ln3g, bw_ln3b,
        hln, hlnbH, hlnbL, out_tv, t);
  }
}

// Round 4
// 2071.024 us; speedup vs baseline: 1.1876x; 1.1876x over previous
//
#include <hip/hip_runtime.h>
#include <hip/hip_bf16.h>

// Sizes
#define U_    1200
#define E_    620
#define B_    128
#define T_    64
#define N3    3600           // 3*U
#define NP    3712           // padded 3U = 29*128
#define KE    640            // padded E  = 10*64
#define KU    1216           // padded U  = 19*64
#define WIN   16             // xproj window (scan steps per window GEMM)
#define LN_EPS 1e-3f

typedef __attribute__((ext_vector_type(8))) short short8;
typedef __attribute__((ext_vector_type(4))) float f32x4;

// ---------------- workspace layout (bytes) ----------------
constexpr size_t OFF_EMBH  = 0;                                   // bf16 [8192][KE] hi
constexpr size_t SZ_EMB    = (size_t)8192 * KE * 2;
constexpr size_t OFF_EMBL  = OFF_EMBH + SZ_EMB;
constexpr size_t OFF_KTH   = OFF_EMBL + SZ_EMB;                   // bf16 [2][NP][KE] hi
constexpr size_t SZ_KT     = (size_t)2 * NP * KE * 2;
constexpr size_t OFF_KTL   = OFF_KTH + SZ_KT;
constexpr size_t OFF_RKTH  = OFF_KTL + SZ_KT;                     // bf16 [2][NP][KU] hi
constexpr size_t SZ_RKT    = (size_t)2 * NP * KU * 2;
constexpr size_t OFF_RKTL  = OFF_RKTH + SZ_RKT;
constexpr size_t OFF_XPWH  = OFF_RKTL + SZ_RKT;                   // bf16 [2][WIN][B][NP] hi
constexpr size_t SZ_XPW    = (size_t)2 * WIN * B_ * NP * 2;
constexpr size_t OFF_XPWL  = OFF_XPWH + SZ_XPW;
constexpr size_t OFF_INNER = OFF_XPWL + SZ_XPW;                   // f32 [2dirs*2kp][B][NP]
constexpr size_t SZ_INNER  = (size_t)4 * B_ * NP * 4;
constexpr size_t OFF_HLN   = OFF_INNER + SZ_INNER;                // f32 [2][B][U]
constexpr size_t SZ_HLN    = (size_t)2 * B_ * U_ * 4;
constexpr size_t OFF_HLNBH = OFF_HLN + SZ_HLN;                    // bf16 [2][B][KU] hi
constexpr size_t SZ_HLNB   = (size_t)2 * B_ * KU * 2;
constexpr size_t OFF_HLNBL = OFF_HLNBH + SZ_HLNB;

__device__ inline void lds_load16(const void* g, void* l) {
  __builtin_amdgcn_global_load_lds(
      (const __attribute__((address_space(1))) unsigned int*)g,
      (__attribute__((address_space(3))) unsigned int*)l, 16, 0, 0);
}

__device__ inline float sigmf(float x) { return 1.f / (1.f + expf(-x)); }

// ---------------- K1: embedding gather + tanh (fp32 out + hi/lo bf16) -----
__global__ __launch_bounds__(256)
void embed_kernel(const int* __restrict__ sent, const float* __restrict__ embed,
                  float* __restrict__ out_emb,
                  __hip_bfloat16* __restrict__ embH, __hip_bfloat16* __restrict__ embL) {
  const int row = blockIdx.x;                 // b*T + t
  const int idx = sent[row];
  const float* src = embed + (size_t)idx * E_;
  for (int e = threadIdx.x; e < KE; e += 256) {
    float v = 0.f;
    if (e < E_) {
      v = tanhf(src[e]);
      out_emb[(size_t)row * E_ + e] = v;
    }
    const __hip_bfloat16 hi = __float2bfloat16(v);
    embH[(size_t)row * KE + e] = hi;
    embL[(size_t)row * KE + e] = __float2bfloat16(v - __bfloat162float(hi));
  }
}

// ---------------- K2: transpose+cast [K][3600]f32 -> [NP][Kp] hi/lo bf16 ---
__global__ __launch_bounds__(256)
void transpose_cast(const float* __restrict__ W0, const float* __restrict__ W1,
                    __hip_bfloat16* __restrict__ WtHi, __hip_bfloat16* __restrict__ WtLo,
                    int Kreal, int Kp) {
  const int d = blockIdx.z;
  const float* W = d ? W1 : W0;
  __hip_bfloat16* dstH = WtHi + (size_t)d * NP * Kp;
  __hip_bfloat16* dstL = WtLo + (size_t)d * NP * Kp;
  __shared__ float tile[32][33];
  const int n0 = blockIdx.x * 32, k0 = blockIdx.y * 32;
  const int tx = threadIdx.x, ty = threadIdx.y;   // 32 x 8
#pragma unroll
  for (int i = 0; i < 32; i += 8) {
    const int k = k0 + ty + i, n = n0 + tx;
    tile[ty + i][tx] = (k < Kreal && n < N3) ? W[(size_t)k * N3 + n] : 0.f;
  }
  __syncthreads();
#pragma unroll
  for (int i = 0; i < 32; i += 8) {
    const int n = n0 + ty + i, k = k0 + tx;
    const float v = tile[tx][ty + i];
    const __hip_bfloat16 hi = __float2bfloat16(v);
    dstH[(size_t)n * Kp + k] = hi;
    dstL[(size_t)n * Kp + k] = __float2bfloat16(v - __bfloat162float(hi));
  }
}

// ---------------- K4: init h_ln = LN(0) = beta ----------------
__global__ __launch_bounds__(256)
void init_hln(const float* __restrict__ fw_b0, const float* __restrict__ bw_b0,
              float* __restrict__ hln, __hip_bfloat16* __restrict__ hlnbH,
              __hip_bfloat16* __restrict__ hlnbL) {
  const int idx = blockIdx.x * 256 + threadIdx.x;   // [2*128*KU]
  if (idx >= 2 * B_ * KU) return;
  const int k = idx % KU;
  const int rowd = idx / KU;
  const int d = rowd >> 7;
  float v = 0.f;
  if (k < U_) {
    v = (d ? bw_b0 : fw_b0)[k];
    hln[(size_t)rowd * U_ + k] = v;
  }
  const __hip_bfloat16 hi = __float2bfloat16(v);
  hlnbH[idx] = hi;
  hlnbL[idx] = __float2bfloat16(v - __bfloat162float(hi));
}

// ---------------- window GEMM: x+ib for WIN scan steps, hi/lo out ---------
// C rows m = srel*B + b  (srel = scan step - w0, b = batch row).
// A row = emb[(b, tx)] where tx = d ? T-1-(w0+srel) : w0+srel.
// 3-term split (hh + hl + lh). 128x128x64 tiles, 4 waves.
__global__ __launch_bounds__(256)
void xwin_gemm(const __hip_bfloat16* __restrict__ embH, const __hip_bfloat16* __restrict__ embL,
               const __hip_bfloat16* __restrict__ kTH, const __hip_bfloat16* __restrict__ kTL,
               const float* __restrict__ fw_bias, const float* __restrict__ bw_bias,
               __hip_bfloat16* __restrict__ xpwH, __hip_bfloat16* __restrict__ xpwL,
               int w0) {
  constexpr int BM = 128, BN = 128, BK = 64;
  constexpr int WM = 64, WN = 64, FM = 4, FN = 4;
  constexpr int TA = BM * BK, TB = BN * BK;       // 8192 elems
  const int d = blockIdx.z;
  const __hip_bfloat16* BH = kTH + (size_t)d * NP * KE;
  const __hip_bfloat16* BL = kTL + (size_t)d * NP * KE;

  const int m0 = blockIdx.y * BM;
  const int n0 = blockIdx.x * BN;
  const int tid = threadIdx.x;
  const int lane = tid & 63;
  const int wid = tid >> 6;
  const int wr = wid >> 1, wc = wid & 1;

  __shared__ __align__(16) __hip_bfloat16 As[2 * TA];
  __shared__ __align__(16) __hip_bfloat16 Bs[2 * TB];

  f32x4 acc[FM][FN] = {};

  const int srow = tid >> 3;
  const int scol = (tid & 7) << 3;

  for (int ks = 0; ks < KE / BK; ++ks) {
    const int k0 = ks * BK;
    __syncthreads();
#pragma unroll
    for (int it = 0; it < TA / 2048; ++it) {
      const int row = m0 + it * 32 + srow;       // m index
      const int b = row & 127, srel = row >> 7;
      const int txi = d ? (T_ - 1 - (w0 + srel)) : (w0 + srel);
      const size_t goff = (size_t)(b * T_ + txi) * KE + k0 + scol;
      lds_load16(embH + goff, As + it * 2048 + tid * 8);
      lds_load16(embL + goff, As + TA + it * 2048 + tid * 8);
    }
#pragma unroll
    for (int it = 0; it < TB / 2048; ++it) {
      const size_t goff = (size_t)(n0 + it * 32 + srow) * KE + k0 + scol;
      lds_load16(BH + goff, Bs + it * 2048 + tid * 8);
      lds_load16(BL + goff, Bs + TB + it * 2048 + tid * 8);
    }
    __syncthreads();
#pragma unroll
    for (int kk = 0; kk < BK / 32; ++kk) {
      short8 ah[FM], al[FM], bh[FN], bl[FN];
#pragma unroll
      for (int mi = 0; mi < FM; ++mi) {
        const int off = (wr * WM + mi * 16 + (lane & 15)) * BK + kk * 32 + (lane >> 4) * 8;
        ah[mi] = *(const short8*)(As + off);
        al[mi] = *(const short8*)(As + TA + off);
      }
#pragma unroll
      for (int ni = 0; ni < FN; ++ni) {
        const int off = (wc * WN + ni * 16 + (lane & 15)) * BK + kk * 32 + (lane >> 4) * 8;
        bh[ni] = *(const short8*)(Bs + off);
        bl[ni] = *(const short8*)(Bs + TB + off);
      }
#pragma unroll
      for (int mi = 0; mi < FM; ++mi)
#pragma unroll
        for (int ni = 0; ni < FN; ++ni) {
          acc[mi][ni] = __builtin_amdgcn_mfma_f32_16x16x32_bf16(ah[mi], bh[ni], acc[mi][ni], 0, 0, 0);
          acc[mi][ni] = __builtin_amdgcn_mfma_f32_16x16x32_bf16(ah[mi], bl[ni], acc[mi][ni], 0, 0, 0);
          acc[mi][ni] = __builtin_amdgcn_mfma_f32_16x16x32_bf16(al[mi], bh[ni], acc[mi][ni], 0, 0, 0);
        }
    }
  }

  const float* ib = d ? bw_bias : fw_bias;
#pragma unroll
  for (int mi = 0; mi < FM; ++mi)
#pragma unroll
    for (int ni = 0; ni < FN; ++ni) {
      const int gc = n0 + wc * WN + ni * 16 + (lane & 15);
      const float bv = (gc < N3) ? ib[gc] : 0.f;
      const int gr0 = m0 + wr * WM + mi * 16 + ((lane >> 4) << 2);
#pragma unroll
      for (int j = 0; j < 4; ++j) {
        const int gr = gr0 + j;
        const int b = gr & 127, srel = gr >> 7;
        const size_t off = ((size_t)(d * WIN + srel) * B_ + b) * NP + gc;
        const float v = acc[mi][ni][j] + bv;
        const __hip_bfloat16 hi = __float2bfloat16(v);
        xpwH[off] = hi;
        xpwL[off] = __float2bfloat16(v - __bfloat162float(hi));
      }
    }
}

// ---------------- per-step rec GEMM: split-K x2, 4-term split -------------
// grid (NP/64, B/64, 4): z = d*2 + kpart. Writes inner[z][B][NP] (fp32 partial).
__global__ __launch_bounds__(256)
void step_rec(const __hip_bfloat16* __restrict__ hlnbH, const __hip_bfloat16* __restrict__ hlnbL,
              const __hip_bfloat16* __restrict__ rkTH, const __hip_bfloat16* __restrict__ rkTL,
              float* __restrict__ inner) {
  constexpr int BM = 64, BN = 64, BK = 64;
  constexpr int WM = 32, WN = 32, FM = 2, FN = 2;
  constexpr int TA = BM * BK, TB = BN * BK;       // 4096
  const int z = blockIdx.z;
  const int d = z >> 1, kp = z & 1;
  const int ks0 = kp ? 10 : 0;
  const int ks1 = kp ? 19 : 10;

  const __hip_bfloat16* BH = rkTH + (size_t)d * NP * KU;
  const __hip_bfloat16* BL = rkTL + (size_t)d * NP * KU;

  const int m0 = blockIdx.y * BM;
  const int n0 = blockIdx.x * BN;
  const int tid = threadIdx.x;
  const int lane = tid & 63;
  const int wid = tid >> 6;
  const int wr = wid >> 1, wc = wid & 1;

  __shared__ __align__(16) __hip_bfloat16 As[2 * TA];
  __shared__ __align__(16) __hip_bfloat16 Bs[2 * TB];

  f32x4 acc[FM][FN] = {};

  const int srow = tid >> 3;
  const int scol = (tid & 7) << 3;

  for (int ks = ks0; ks < ks1; ++ks) {
    const int k0 = ks * BK;
    __syncthreads();
#pragma unroll
    for (int it = 0; it < TA / 2048; ++it) {
      const int row = m0 + it * 32 + srow;       // batch row
      const size_t goff = (size_t)(d * B_ + row) * KU + k0 + scol;
      lds_load16(hlnbH + goff, As + it * 2048 + tid * 8);
      lds_load16(hlnbL + goff, As + TA + it * 2048 + tid * 8);
    }
#pragma unroll
    for (int it = 0; it < TB / 2048; ++it) {
      const size_t goff = (size_t)(n0 + it * 32 + srow) * KU + k0 + scol;
      lds_load16(BH + goff, Bs + it * 2048 + tid * 8);
      lds_load16(BL + goff, Bs + TB + it * 2048 + tid * 8);
    }
    __syncthreads();
#pragma unroll
    for (int kk = 0; kk < BK / 32; ++kk) {
      short8 ah[FM], al[FM], bh[FN], bl[FN];
#pragma unroll
      for (int mi = 0; mi < FM; ++mi) {
        const int off = (wr * WM + mi * 16 + (lane & 15)) * BK + kk * 32 + (lane >> 4) * 8;
        ah[mi] = *(const short8*)(As + off);
        al[mi] = *(const short8*)(As + TA + off);
      }
#pragma unroll
      for (int ni = 0; ni < FN; ++ni) {
        const int off = (wc * WN + ni * 16 + (lane & 15)) * BK + kk * 32 + (lane >> 4) * 8;
        bh[ni] = *(const short8*)(Bs + off);
        bl[ni] = *(const short8*)(Bs + TB + off);
      }
#pragma unroll
      for (int mi = 0; mi < FM; ++mi)
#pragma unroll
        for (int ni = 0; ni < FN; ++ni) {
          acc[mi][ni] = __builtin_amdgcn_mfma_f32_16x16x32_bf16(ah[mi], bh[ni], acc[mi][ni], 0, 0, 0);
          acc[mi][ni] = __builtin_amdgcn_mfma_f32_16x16x32_bf16(ah[mi], bl[ni], acc[mi][ni], 0, 0, 0);
          acc[mi][ni] = __builtin_amdgcn_mfma_f32_16x16x32_bf16(al[mi], bh[ni], acc[mi][ni], 0, 0, 0);
          acc[mi][ni] = __builtin_amdgcn_mfma_f32_16x16x32_bf16(al[mi], bl[ni], acc[mi][ni], 0, 0, 0);
        }
    }
  }

  float* C = inner + (size_t)z * B_ * NP;
#pragma unroll
  for (int mi = 0; mi < FM; ++mi)
#pragma unroll
    for (int ni = 0; ni < FN; ++ni) {
      const int gc = n0 + wc * WN + ni * 16 + (lane & 15);
      const int gr = m0 + wr * WM + mi * 16 + ((lane >> 4) << 2);
#pragma unroll
      for (int j = 0; j < 4; ++j)
        C[(size_t)(gr + j) * NP + gc] = acc[mi][ni][j];
    }
}

// ---------------- block-wide 2-value sum reduction ----------------
__device__ inline void breduce2(float& a, float& b, float* red, int tid) {
#pragma unroll
  for (int off = 32; off; off >>= 1) {
    a += __shfl_down(a, off, 64);
    b += __shfl_down(b, off, 64);
  }
  const int w = tid >> 6;
  __syncthreads();
  if ((tid & 63) == 0) { red[w] = a; red[4 + w] = b; }
  __syncthreads();
  a = red[0] + red[1] + red[2] + red[3];
  b = red[4] + red[5] + red[6] + red[7];
}

// ---------------- K6: per-row GRU update (one block per (dir,row)) --------
__global__ __launch_bounds__(256)
void gru_update(const float* __restrict__ inner,
                const __hip_bfloat16* __restrict__ xpwH, const __hip_bfloat16* __restrict__ xpwL,
                const float* __restrict__ fw_bias, const float* __restrict__ bw_bias,
                const float* __restrict__ fw_ln0g, const float* __restrict__ fw_ln0b,
                const float* __restrict__ fw_ln3g, const float* __restrict__ fw_ln3b,
                const float* __restrict__ bw_ln0g, const float* __restrict__ bw_ln0b,
                const float* __restrict__ bw_ln3g, const float* __restrict__ bw_ln3b,
                float* __restrict__ hln, __hip_bfloat16* __restrict__ hlnbH,
                __hip_bfloat16* __restrict__ hlnbL,
                float* __restrict__ out_tv, int srel, int t) {
  const int bid = blockIdx.x;
  const int d = bid >> 7;
  const int r = bid & 127;
  const int tid = threadIdx.x;

  const float* rec0 = inner + ((size_t)(d * 2 + 0) * B_ + r) * NP;
  const float* rec1 = inner + ((size_t)(d * 2 + 1) * B_ + r) * NP;
  const size_t xoff = ((size_t)(d * WIN + srel) * B_ + r) * NP;
  const __hip_bfloat16* xH = xpwH + xoff;
  const __hip_bfloat16* xL = xpwL + xoff;
  const float* rb = (d ? bw_bias : fw_bias) + N3;   // recurrent bias row
  const float* g0 = d ? bw_ln0g : fw_ln0g;
  const float* b0 = d ? bw_ln0b : fw_ln0b;
  const float* g3 = d ? bw_ln3g : fw_ln3g;
  const float* b3 = d ? bw_ln3b : fw_ln3b;
  float* hl = hln + ((size_t)d * B_ + r) * U_;
  __hip_bfloat16* hlbH = hlnbH + ((size_t)d * B_ + r) * KU;
  __hip_bfloat16* hlbL = hlnbL + ((size_t)d * B_ + r) * KU;

  __shared__ float red[8];

  float zv[5], cv[5], hv[5];
  float s1 = 0.f, s2 = 0.f;
#pragma unroll
  for (int i = 0; i < 5; ++i) {
    const int c = tid + i * 256;
    if (c < U_) {
      const float xz = __bfloat162float(xH[c]) + __bfloat162float(xL[c]);
      const float xg = __bfloat162float(xH[U_ + c]) + __bfloat162float(xL[U_ + c]);
      const float xh = __bfloat162float(xH[2 * U_ + c]) + __bfloat162float(xL[2 * U_ + c]);
      const float z  = sigmf(xz + rec0[c] + rec1[c] + rb[c]);
      const float rr = sigmf(xg + rec0[U_ + c] + rec1[U_ + c] + rb[U_ + c]);
      const float cand = xh + rr * (rec0[2 * U_ + c] + rec1[2 * U_ + c] + rb[2 * U_ + c]);
      zv[i] = z; cv[i] = cand;
      s1 += cand; s2 += cand * cand;
    }
  }
  breduce2(s1, s2, red, tid);
  const float m1 = s1 / U_;
  const float is1 = rsqrtf(s2 / U_ - m1 * m1 + LN_EPS);

  float t1 = 0.f, t2 = 0.f;
#pragma unroll
  for (int i = 0; i < 5; ++i) {
    const int c = tid + i * 256;
    if (c < U_) {
      const float hh = tanhf(g3[c] * (cv[i] - m1) * is1 + b3[c]);
      const float hn = zv[i] * hl[c] + (1.f - zv[i]) * hh;
      hv[i] = hn;
      t1 += hn; t2 += hn * hn;
    }
  }
  breduce2(t1, t2, red, tid);
  const float m2 = t1 / U_;
  const float is2 = rsqrtf(t2 / U_ - m2 * m2 + LN_EPS);

#pragma unroll
  for (int i = 0; i < 5; ++i) {
    const int c = tid + i * 256;
    if (c < U_) {
      const float hlnew = g0[c] * (hv[i] - m2) * is2 + b0[c];
      hl[c] = hlnew;
      const __hip_bfloat16 hi = __float2bfloat16(hlnew);
      hlbH[c] = hi;
      hlbL[c] = __float2bfloat16(hlnew - __bfloat162float(hi));
      if (t == T_ - 1) out_tv[(size_t)r * 2400 + (size_t)d * U_ + c] = hv[i];
    }
  }
}

// ---------------- host-side launch ----------------
extern "C" void kernel_launch(void* const* d_in, const int* in_sizes, int n_in,
                              void* d_out, int out_size, void* d_ws, size_t ws_size,
                              hipStream_t stream) {
  const int*   sent      = (const int*)  d_in[0];
  const float* embed     = (const float*)d_in[1];
  const float* fw_kernel = (const float*)d_in[2];
  const float* fw_rkern  = (const float*)d_in[3];
  const float* fw_bias   = (const float*)d_in[4];
  const float* fw_ln0g   = (const float*)d_in[5];
  const float* fw_ln0b   = (const float*)d_in[6];
  const float* fw_ln3g   = (const float*)d_in[7];
  const float* fw_ln3b   = (const float*)d_in[8];
  const float* bw_kernel = (const float*)d_in[9];
  const float* bw_rkern  = (const float*)d_in[10];
  const float* bw_bias   = (const float*)d_in[11];
  const float* bw_ln0g   = (const float*)d_in[12];
  const float* bw_ln0b   = (const float*)d_in[13];
  const float* bw_ln3g   = (const float*)d_in[14];
  const float* bw_ln3b   = (const float*)d_in[15];

  uint8_t* ws = (uint8_t*)d_ws;
  __hip_bfloat16* embH  = (__hip_bfloat16*)(ws + OFF_EMBH);
  __hip_bfloat16* embL  = (__hip_bfloat16*)(ws + OFF_EMBL);
  __hip_bfloat16* kTH   = (__hip_bfloat16*)(ws + OFF_KTH);
  __hip_bfloat16* kTL   = (__hip_bfloat16*)(ws + OFF_KTL);
  __hip_bfloat16* rkTH  = (__hip_bfloat16*)(ws + OFF_RKTH);
  __hip_bfloat16* rkTL  = (__hip_bfloat16*)(ws + OFF_RKTL);
  __hip_bfloat16* xpwH  = (__hip_bfloat16*)(ws + OFF_XPWH);
  __hip_bfloat16* xpwL  = (__hip_bfloat16*)(ws + OFF_XPWL);
  float*          inner = (float*)(ws + OFF_INNER);
  float*          hln   = (float*)(ws + OFF_HLN);
  __hip_bfloat16* hlnbH = (__hip_bfloat16*)(ws + OFF_HLNBH);
  __hip_bfloat16* hlnbL = (__hip_bfloat16*)(ws + OFF_HLNBL);

  float* out_tv  = (float*)d_out;                        // [128][2400]
  float* out_emb = (float*)d_out + (size_t)B_ * 2 * U_;  // [8192][620]

  // K1: embedding gather + tanh (fp32 + hi/lo bf16 planes)
  embed_kernel<<<B_ * T_, 256, 0, stream>>>(sent, embed, out_emb, embH, embL);

  // K2: weight transpose+cast hi/lo (both dirs each)
  transpose_cast<<<dim3(NP / 32, KE / 32, 2), dim3(32, 8), 0, stream>>>(
      fw_kernel, bw_kernel, kTH, kTL, E_, KE);
  transpose_cast<<<dim3(NP / 32, KU / 32, 2), dim3(32, 8), 0, stream>>>(
      fw_rkern, bw_rkern, rkTH, rkTL, U_, KU);

  // K4: h_ln = LN(0) = beta
  init_hln<<<(2 * B_ * KU + 255) / 256, 256, 0, stream>>>(fw_ln0b, bw_ln0b,
                                                          hln, hlnbH, hlnbL);

  // scan: windowed x-projection hoist + per-step rec GEMM (split-K2) + update
  for (int w0 = 0; w0 < T_; w0 += WIN) {
    xwin_gemm<<<dim3(NP / 128, (WIN * B_) / 128, 2), 256, 0, stream>>>(
        embH, embL, kTH, kTL, fw_bias, bw_bias, xpwH, xpwL, w0);
    for (int s = 0; s < WIN; ++s) {
      const int t = w0 + s;
      step_rec<<<dim3(NP / 64, B_ / 64, 4), 256, 0, stream>>>(
          hlnbH, hlnbL, rkTH, rkTL, inner);
      gru_update<<<2 * B_, 256, 0, stream>>>(
          inner, xpwH, xpwL, fw_bias, bw_bias,
          fw_ln0g, fw_ln0b, fw_ln3g, fw_ln3b,
          bw_ln0g, bw_ln0b, bw_ln3g, bw_ln3b,
          hln, hlnbH, hlnbL, out_tv, s, t);
    }
  }
}